// Round 1
// baseline (1293.408 us; speedup 1.0000x reference)
//
#include <hip/hip_runtime.h>
#include <hip/hip_bf16.h>

#define T_TOK 4096
#define HID   2048
#define FFN_D 4096
#define NE    8
#define BM    128
#define BN    128
#define BK    64

typedef __attribute__((ext_vector_type(8))) short  short8;
typedef __attribute__((ext_vector_type(4))) float  f32x4;
typedef __attribute__((ext_vector_type(4))) unsigned short u16x4;
typedef unsigned short u16;

__device__ __forceinline__ u16 f2bf(float f) {
    unsigned u = __float_as_uint(f);
    u += 0x7FFFu + ((u >> 16) & 1u);   // RNE
    return (u16)(u >> 16);
}
__device__ __forceinline__ float bf2f(u16 v) {
    return __uint_as_float(((unsigned)v) << 16);
}

// ---------------- K0: x fp32 -> bf16 ----------------
__global__ void k_convert_x(const float* __restrict__ x, u16* __restrict__ xb) {
    int i = blockIdx.x * 256 + threadIdx.x;        // exactly T*H/8 threads
    const f32x4* src = (const f32x4*)x + (size_t)i * 2;
    f32x4 a = src[0], b = src[1];
    short8 o;
#pragma unroll
    for (int q = 0; q < 4; ++q) { o[q] = (short)f2bf(a[q]); o[q + 4] = (short)f2bf(b[q]); }
    *(short8*)(xb + (size_t)i * 8) = o;
}

// ---------------- K1: router (1 wave per token) ----------------
__global__ void k_router(const float* __restrict__ x, const float* __restrict__ wr,
                         int* __restrict__ topk_id, float* __restrict__ topk_w,
                         int* __restrict__ counts) {
    int lane = threadIdx.x & 63;
    int t = blockIdx.x * 4 + (threadIdx.x >> 6);
    const float* xr = x + (size_t)t * HID;
    float acc[8];
#pragma unroll
    for (int e = 0; e < 8; ++e) acc[e] = 0.f;
    for (int h = lane; h < HID; h += 64) {
        float xv = xr[h];
        f32x4 w0 = *(const f32x4*)(wr + h * 8);
        f32x4 w1 = *(const f32x4*)(wr + h * 8 + 4);
#pragma unroll
        for (int q = 0; q < 4; ++q) { acc[q] += xv * w0[q]; acc[4 + q] += xv * w1[q]; }
    }
#pragma unroll
    for (int e = 0; e < 8; ++e) {
        float v = acc[e];
#pragma unroll
        for (int s = 32; s > 0; s >>= 1) v += __shfl_xor(v, s);
        acc[e] = v;
    }
    if (lane == 0) {
        int i0 = 0; float l0 = acc[0];
#pragma unroll
        for (int e = 1; e < 8; ++e) if (acc[e] > l0) { l0 = acc[e]; i0 = e; }
        int i1 = -1; float l1 = -3.4e38f;
#pragma unroll
        for (int e = 0; e < 8; ++e) if (e != i0 && acc[e] > l1) { l1 = acc[e]; i1 = e; }
        // top-2 renormalized softmax: denominator cancels
        float wA = 1.f / (1.f + expf(l1 - l0));
        topk_id[t * 2] = i0;  topk_id[t * 2 + 1] = i1;
        topk_w[t * 2] = wA;   topk_w[t * 2 + 1] = 1.f - wA;
        atomicAdd(&counts[i0], 1);
        atomicAdd(&counts[i1], 1);
    }
}

// ---------------- K2: padded scan + fill ----------------
__global__ void k_scan(const int* __restrict__ counts, int* __restrict__ pad_off,
                       int* __restrict__ perm_tok) {
    __shared__ int sTot;
    if (threadIdx.x == 0) {
        int o = 0;
#pragma unroll
        for (int e = 0; e < 8; ++e) { pad_off[e] = o; o += ((counts[e] + BM - 1) / BM) * BM; }
        pad_off[8] = o; sTot = o;
    }
    __syncthreads();
    int tot = sTot;
    for (int i = threadIdx.x; i < tot; i += 256) perm_tok[i] = 0;  // filler = token 0
}

// ---------------- K3: scatter tokens into expert lists ----------------
__global__ void k_scatter(const int* __restrict__ topk_id, int* __restrict__ cursors,
                          const int* __restrict__ pad_off, int* __restrict__ perm_tok,
                          int* __restrict__ pos_of) {
    int t = blockIdx.x * 256 + threadIdx.x;
    if (t >= T_TOK) return;
#pragma unroll
    for (int k = 0; k < 2; ++k) {
        int e = topk_id[t * 2 + k];
        int p = pad_off[e] + atomicAdd(&cursors[e], 1);
        perm_tok[p] = t;
        pos_of[t * 2 + k] = p;
    }
}

// ---------------- K4/K5: tiled bf16 MFMA GEMM (NT), optional dual-B + SwiGLU ----
// A [rows, KTOT] bf16 (optionally gathered rows), B [NTOT, KTOT] fp32 per expert
// (converted to bf16 in staging), C [pad_rows, NTOT] bf16.
template<int KTOT, int NTOT, bool DUAL, bool GATHER>
__global__ __launch_bounds__(256) void k_gemm(
    const u16* __restrict__ A,
    const float* __restrict__ Ball0,
    const float* __restrict__ Ball1,
    u16* __restrict__ C,
    const int* __restrict__ perm_tok,
    const int* __restrict__ pad_off)
{
    const int e    = blockIdx.z;
    const int base = pad_off[e];
    const int ne   = pad_off[e + 1] - base;         // padded count (multiple of BM)
    const int m0   = blockIdx.y * BM;
    if (m0 >= ne) return;                            // uniform early-exit
    const int n0  = blockIdx.x * BN;
    const int tid = threadIdx.x;

    __shared__ u16 As[BM * BK];
    __shared__ u16 Bs0[BN * BK];
    __shared__ u16 Bs1[DUAL ? BN * BK : 8];
    __shared__ int tokS[BM];

    const float* B0 = Ball0 + (size_t)e * NTOT * KTOT;
    const float* B1 = DUAL ? (Ball1 + (size_t)e * NTOT * KTOT) : Ball0;

    if (GATHER) {
        if (tid < BM) tokS[tid] = perm_tok[base + m0 + tid];
        __syncthreads();
    }

    const int sr = tid >> 3;   // staging row within 32-row group
    const int sc = tid & 7;    // 16B chunk within row

    const u16*   aRow[4];
    const float* b0Row[4];
    const float* b1Row[4];
    int dIdx[4];
#pragma unroll
    for (int i = 0; i < 4; ++i) {
        int r = sr + 32 * i;
        if (GATHER) aRow[i] = A + (size_t)tokS[r] * KTOT + sc * 8;
        else        aRow[i] = A + (size_t)(base + m0 + r) * KTOT + sc * 8;
        b0Row[i] = B0 + (size_t)(n0 + r) * KTOT + sc * 8;
        b1Row[i] = B1 + (size_t)(n0 + r) * KTOT + sc * 8;
        dIdx[i] = r * BK + ((sc ^ (sr & 7)) << 3);   // XOR-swizzled 16B chunk
    }

    const int lane = tid & 63;
    const int wid  = tid >> 6;
    const int wm   = (wid >> 1) * 64;
    const int wn   = (wid & 1) * 64;
    const int fr   = lane & 15;
    const int fk   = lane >> 4;
    const int x7   = fr & 7;

    f32x4 acc0[4][4], acc1[4][4];
    const f32x4 fz = {0.f, 0.f, 0.f, 0.f};
#pragma unroll
    for (int i = 0; i < 4; ++i)
#pragma unroll
        for (int j = 0; j < 4; ++j) { acc0[i][j] = fz; acc1[i][j] = fz; }

    for (int ks = 0; ks < KTOT / BK; ++ks) {
        short8 av[4], b0s[4], b1s[4];
#pragma unroll
        for (int i = 0; i < 4; ++i) {
            av[i] = *(const short8*)(aRow[i]);  aRow[i] += BK;
            f32x4 f0 = *(const f32x4*)(b0Row[i]);
            f32x4 f1 = *(const f32x4*)(b0Row[i] + 4);  b0Row[i] += BK;
#pragma unroll
            for (int q = 0; q < 4; ++q) { b0s[i][q] = (short)f2bf(f0[q]); b0s[i][q + 4] = (short)f2bf(f1[q]); }
            if (DUAL) {
                f32x4 g0 = *(const f32x4*)(b1Row[i]);
                f32x4 g1 = *(const f32x4*)(b1Row[i] + 4);  b1Row[i] += BK;
#pragma unroll
                for (int q = 0; q < 4; ++q) { b1s[i][q] = (short)f2bf(g0[q]); b1s[i][q + 4] = (short)f2bf(g1[q]); }
            }
        }
        __syncthreads();   // previous tile's reads done
#pragma unroll
        for (int i = 0; i < 4; ++i) {
            *(short8*)(&As[dIdx[i]])  = av[i];
            *(short8*)(&Bs0[dIdx[i]]) = b0s[i];
            if (DUAL) *(short8*)(&Bs1[dIdx[i]]) = b1s[i];
        }
        __syncthreads();   // tile ready
#pragma unroll
        for (int kk = 0; kk < 2; ++kk) {
            short8 af[4], b0f[4], b1f[4];
            const int ct = ((kk * 4 + fk) ^ x7) << 3;
#pragma unroll
            for (int i = 0; i < 4; ++i) af[i]  = *(const short8*)(&As[(wm + i * 16 + fr) * BK + ct]);
#pragma unroll
            for (int j = 0; j < 4; ++j) b0f[j] = *(const short8*)(&Bs0[(wn + j * 16 + fr) * BK + ct]);
            if (DUAL) {
#pragma unroll
                for (int j = 0; j < 4; ++j) b1f[j] = *(const short8*)(&Bs1[(wn + j * 16 + fr) * BK + ct]);
            }
#pragma unroll
            for (int i = 0; i < 4; ++i)
#pragma unroll
                for (int j = 0; j < 4; ++j) {
                    acc0[i][j] = __builtin_amdgcn_mfma_f32_16x16x32_bf16(af[i], b0f[j], acc0[i][j], 0, 0, 0);
                    if (DUAL)
                        acc1[i][j] = __builtin_amdgcn_mfma_f32_16x16x32_bf16(af[i], b1f[j], acc1[i][j], 0, 0, 0);
                }
        }
        __syncthreads();   // compute done before next overwrite
    }

    // epilogue: C/D layout col=lane&15, row=(lane>>4)*4+reg
    const int er = (lane >> 4) * 4;
    const int ec = lane & 15;
#pragma unroll
    for (int i = 0; i < 4; ++i)
#pragma unroll
        for (int j = 0; j < 4; ++j)
#pragma unroll
            for (int r = 0; r < 4; ++r) {
                size_t prow = (size_t)(base + m0 + wm + i * 16 + er + r);
                int col = n0 + wn + j * 16 + ec;
                float v = acc0[i][j][r];
                float res;
                if (DUAL) {
                    float g3 = acc1[i][j][r];
                    res = v / (1.f + __expf(-v)) * g3;   // silu(g1)*g3
                } else {
                    res = v;
                }
                C[prow * NTOT + col] = f2bf(res);
            }
}

// ---------------- K6: weighted combine ----------------
__global__ void k_combine(const u16* __restrict__ y, const int* __restrict__ pos_of,
                          const float* __restrict__ topk_w, float* __restrict__ out) {
    int idx = blockIdx.x * 256 + threadIdx.x;    // exactly T * (H/4)
    int t  = idx >> 9;
    int c4 = (idx & 511) << 2;
    int p0 = pos_of[t * 2], p1 = pos_of[t * 2 + 1];
    float w0 = topk_w[t * 2], w1 = topk_w[t * 2 + 1];
    u16x4 a = *(const u16x4*)(y + (size_t)p0 * HID + c4);
    u16x4 b = *(const u16x4*)(y + (size_t)p1 * HID + c4);
    f32x4 o;
#pragma unroll
    for (int q = 0; q < 4; ++q) o[q] = w0 * bf2f(a[q]) + w1 * bf2f(b[q]);
    *(f32x4*)(out + (size_t)t * HID + c4) = o;
    if (idx == 0) out[(size_t)T_TOK * HID] = 0.f;   // second output: zeros((1,))
}

__global__ void k_init(int* __restrict__ c) {
    if (threadIdx.x < 16) c[threadIdx.x] = 0;       // counts[8] + cursors[8]
}

extern "C" void kernel_launch(void* const* d_in, const int* in_sizes, int n_in,
                              void* d_out, int out_size, void* d_ws, size_t ws_size,
                              hipStream_t stream) {
    const float* x  = (const float*)d_in[0];
    const float* wr = (const float*)d_in[1];
    const float* w1 = (const float*)d_in[2];
    const float* w2 = (const float*)d_in[3];
    const float* w3 = (const float*)d_in[4];
    float* out = (float*)d_out;

    char* ws = (char*)d_ws;
    u16*  xb       = (u16*)(ws);                    // 16,777,216 B
    u16*  hbuf     = (u16*)(ws + 16777216);         // 75,497,472 B (9216 x 4096 bf16)
    u16*  ybuf     = (u16*)(ws + 92274688);         // 37,748,736 B (9216 x 2048 bf16)
    int*  perm_tok = (int*)(ws + 130023424);        // 9216 ints
    int*  pos_of   = (int*)(ws + 130060288);        // 8192 ints
    int*  topk_id  = (int*)(ws + 130093056);        // 8192 ints
    float* topk_w  = (float*)(ws + 130125824);      // 8192 floats
    int*  cnt      = (int*)(ws + 130158592);        // counts[8], cursors[8], pad_off[9]
    int*  counts   = cnt;
    int*  cursors  = cnt + 8;
    int*  pad_off  = cnt + 16;

    k_init<<<1, 64, 0, stream>>>(cnt);
    k_convert_x<<<4096, 256, 0, stream>>>(x, xb);
    k_router<<<1024, 256, 0, stream>>>(x, wr, topk_id, topk_w, counts);
    k_scan<<<1, 256, 0, stream>>>(counts, pad_off, perm_tok);
    k_scatter<<<16, 256, 0, stream>>>(topk_id, cursors, pad_off, perm_tok, pos_of);

    // stage 1: h = silu(x@w1^T) * (x@w3^T), gathered rows, dual-B fused
    k_gemm<HID, FFN_D, true, true><<<dim3(FFN_D / BN, 32, NE), 256, 0, stream>>>(
        xb, w1, w3, hbuf, perm_tok, pad_off);
    // stage 2: y = h @ w2^T
    k_gemm<FFN_D, HID, false, false><<<dim3(HID / BN, 32, NE), 256, 0, stream>>>(
        hbuf, w2, (const float*)nullptr, ybuf, perm_tok, pad_off);

    k_combine<<<8192, 256, 0, stream>>>(ybuf, pos_of, topk_w, out);
}

// Round 2
// 1242.181 us; speedup vs baseline: 1.0412x; 1.0412x over previous
//
#include <hip/hip_runtime.h>
#include <hip/hip_bf16.h>
#include <stdint.h>

#define T_TOK 4096
#define HID   2048
#define FFN_D 4096
#define NE    8
#define BM    128
#define BN    128
#define BK    64

typedef __attribute__((ext_vector_type(8))) short  short8;
typedef __attribute__((ext_vector_type(4))) float  f32x4;
typedef __attribute__((ext_vector_type(4))) unsigned short u16x4;
typedef unsigned short u16;

__device__ __forceinline__ u16 f2bf(float f) {
    unsigned u = __float_as_uint(f);
    u += 0x7FFFu + ((u >> 16) & 1u);   // RNE
    return (u16)(u >> 16);
}
__device__ __forceinline__ float bf2f(u16 v) {
    return __uint_as_float(((unsigned)v) << 16);
}

// direct global->LDS, 16B per lane; LDS dest = wave-uniform base + lane*16
#define GLD16(g, l) __builtin_amdgcn_global_load_lds( \
    (const __attribute__((address_space(1))) unsigned int*)(g), \
    (__attribute__((address_space(3))) unsigned int*)(l), 16, 0, 0)

// ---------------- generic fp32 -> bf16 converter (grid-stride, x8 vectorized) ----
__global__ void k_convert(const float* __restrict__ s, u16* __restrict__ d, long n8) {
    for (long i = (long)blockIdx.x * 256 + threadIdx.x; i < n8; i += (long)gridDim.x * 256) {
        f32x4 a = *((const f32x4*)s + i * 2);
        f32x4 b = *((const f32x4*)s + i * 2 + 1);
        short8 o;
#pragma unroll
        for (int q = 0; q < 4; ++q) { o[q] = (short)f2bf(a[q]); o[q + 4] = (short)f2bf(b[q]); }
        *(short8*)(d + i * 8) = o;
    }
}

// ---------------- router (1 wave per token) ----------------
__global__ void k_router(const float* __restrict__ x, const float* __restrict__ wr,
                         int* __restrict__ topk_id, float* __restrict__ topk_w,
                         int* __restrict__ counts) {
    int lane = threadIdx.x & 63;
    int t = blockIdx.x * 4 + (threadIdx.x >> 6);
    const float* xr = x + (size_t)t * HID;
    float acc[8];
#pragma unroll
    for (int e = 0; e < 8; ++e) acc[e] = 0.f;
    for (int h = lane; h < HID; h += 64) {
        float xv = xr[h];
        f32x4 w0 = *(const f32x4*)(wr + h * 8);
        f32x4 w1 = *(const f32x4*)(wr + h * 8 + 4);
#pragma unroll
        for (int q = 0; q < 4; ++q) { acc[q] += xv * w0[q]; acc[4 + q] += xv * w1[q]; }
    }
#pragma unroll
    for (int e = 0; e < 8; ++e) {
        float v = acc[e];
#pragma unroll
        for (int s = 32; s > 0; s >>= 1) v += __shfl_xor(v, s);
        acc[e] = v;
    }
    if (lane == 0) {
        int i0 = 0; float l0 = acc[0];
#pragma unroll
        for (int e = 1; e < 8; ++e) if (acc[e] > l0) { l0 = acc[e]; i0 = e; }
        int i1 = -1; float l1 = -3.4e38f;
#pragma unroll
        for (int e = 0; e < 8; ++e) if (e != i0 && acc[e] > l1) { l1 = acc[e]; i1 = e; }
        float wA = 1.f / (1.f + expf(l1 - l0));   // top-2 softmax renorm, denom cancels
        topk_id[t * 2] = i0;  topk_id[t * 2 + 1] = i1;
        topk_w[t * 2] = wA;   topk_w[t * 2 + 1] = 1.f - wA;
        atomicAdd(&counts[i0], 1);
        atomicAdd(&counts[i1], 1);
    }
}

// ---------------- padded scan + fill ----------------
__global__ void k_scan(const int* __restrict__ counts, int* __restrict__ pad_off,
                       int* __restrict__ perm_tok) {
    __shared__ int sTot;
    if (threadIdx.x == 0) {
        int o = 0;
#pragma unroll
        for (int e = 0; e < 8; ++e) { pad_off[e] = o; o += ((counts[e] + BM - 1) / BM) * BM; }
        pad_off[8] = o; sTot = o;
    }
    __syncthreads();
    int tot = sTot;
    for (int i = threadIdx.x; i < tot; i += 256) perm_tok[i] = 0;  // filler = token 0
}

// ---------------- scatter tokens into expert lists ----------------
__global__ void k_scatter(const int* __restrict__ topk_id, int* __restrict__ cursors,
                          const int* __restrict__ pad_off, int* __restrict__ perm_tok,
                          int* __restrict__ pos_of) {
    int t = blockIdx.x * 256 + threadIdx.x;
    if (t >= T_TOK) return;
#pragma unroll
    for (int k = 0; k < 2; ++k) {
        int e = topk_id[t * 2 + k];
        int p = pad_off[e] + atomicAdd(&cursors[e], 1);
        perm_tok[p] = t;
        pos_of[t * 2 + k] = p;
    }
}

// ---------------- m97-style bf16 MFMA GEMM (NT), global_load_lds staging -------
// A [rows, KTOT] bf16 (optionally gathered rows), B [NTOT, KTOT] bf16 per expert,
// C [pad_rows, NTOT] bf16.
template<int KTOT, int NTOT, bool GATHER>
__global__ __launch_bounds__(256) void k_gemm(
    const u16* __restrict__ A,
    const u16* __restrict__ Ball,
    u16* __restrict__ C,
    const int* __restrict__ perm_tok,
    const int* __restrict__ pad_off)
{
    const int e    = blockIdx.z;
    const int base = pad_off[e];
    const int ne   = pad_off[e + 1] - base;         // padded count (multiple of BM)
    const int m0   = blockIdx.y * BM;
    if (m0 >= ne) return;                            // uniform early-exit
    const int n0  = blockIdx.x * BN;
    const int tid = threadIdx.x;

    __shared__ u16 As[BM * BK];                      // linear [row][64]
    __shared__ u16 Bs[BN * BK];
    __shared__ int tokS[BM];

    const u16* B = Ball + (size_t)e * NTOT * KTOT;

    if (GATHER) {
        if (tid < BM) tokS[tid] = perm_tok[base + m0 + tid];
        __syncthreads();
    }

    const int w = tid >> 6, l = tid & 63;
    // 16 segments of 1KB (8 rows x 128B each); wave w owns segments w*4..w*4+3
    const u16* aSrc[4];
    const u16* bSrc[4];
    u16* aDst[4];
    u16* bDst[4];
#pragma unroll
    for (int s = 0; s < 4; ++s) {
        int gs  = w * 4 + s;
        int row = gs * 8 + (l >> 3);
        int ch  = l & 7;
        size_t arow = GATHER ? (size_t)tokS[row] : (size_t)(base + m0 + row);
        aSrc[s] = A + arow * KTOT + ch * 8;
        bSrc[s] = B + (size_t)(n0 + row) * KTOT + ch * 8;
        aDst[s] = &As[gs * 512];                    // wave-uniform base
        bDst[s] = &Bs[gs * 512];
    }

    const int lane = tid & 63;
    const int wid  = tid >> 6;
    const int wm   = (wid >> 1) * 64;
    const int wn   = (wid & 1) * 64;
    const int fr   = lane & 15;
    const int fk   = lane >> 4;

    f32x4 acc[4][4];
    const f32x4 fz = {0.f, 0.f, 0.f, 0.f};
#pragma unroll
    for (int i = 0; i < 4; ++i)
#pragma unroll
        for (int j = 0; j < 4; ++j) acc[i][j] = fz;

    for (int ks = 0; ks < KTOT / BK; ++ks) {
        __syncthreads();                             // prev tile's reads done
#pragma unroll
        for (int s = 0; s < 4; ++s) {
            GLD16(aSrc[s], aDst[s]);  aSrc[s] += BK;
            GLD16(bSrc[s], bDst[s]);  bSrc[s] += BK;
        }
        __syncthreads();                             // vmcnt(0) drain -> tile ready
#pragma unroll
        for (int kk = 0; kk < 2; ++kk) {
            short8 af[4], bf[4];
            const int ct = (kk * 4 + fk) * 8;
#pragma unroll
            for (int i = 0; i < 4; ++i) af[i] = *(const short8*)(&As[(wm + i * 16 + fr) * BK + ct]);
#pragma unroll
            for (int j = 0; j < 4; ++j) bf[j] = *(const short8*)(&Bs[(wn + j * 16 + fr) * BK + ct]);
#pragma unroll
            for (int i = 0; i < 4; ++i)
#pragma unroll
                for (int j = 0; j < 4; ++j)
                    acc[i][j] = __builtin_amdgcn_mfma_f32_16x16x32_bf16(af[i], bf[j], acc[i][j], 0, 0, 0);
        }
    }

    // epilogue: C/D layout col=lane&15, row=(lane>>4)*4+reg
    const int er = (lane >> 4) * 4;
    const int ec = lane & 15;
#pragma unroll
    for (int i = 0; i < 4; ++i)
#pragma unroll
        for (int j = 0; j < 4; ++j)
#pragma unroll
            for (int r = 0; r < 4; ++r) {
                size_t prow = (size_t)(base + m0 + wm + i * 16 + er + r);
                int col = n0 + wn + j * 16 + ec;
                C[prow * NTOT + col] = f2bf(acc[i][j][r]);
            }
}

// ---------------- fused SwiGLU: g1 = silu(g1) * g3, in place, bf16 ----------------
__global__ void k_swiglu(u16* __restrict__ g1, const u16* __restrict__ g3,
                         const int* __restrict__ pad_off) {
    long n8 = (long)pad_off[8] * (FFN_D / 8);
    for (long i = (long)blockIdx.x * 256 + threadIdx.x; i < n8; i += (long)gridDim.x * 256) {
        short8 a = *(const short8*)(g1 + i * 8);
        short8 b = *(const short8*)(g3 + i * 8);
        short8 o;
#pragma unroll
        for (int q = 0; q < 8; ++q) {
            float v = bf2f((u16)a[q]);
            float u = bf2f((u16)b[q]);
            o[q] = (short)f2bf(v / (1.f + __expf(-v)) * u);
        }
        *(short8*)(g1 + i * 8) = o;
    }
}

// ---------------- weighted combine ----------------
__global__ void k_combine(const u16* __restrict__ y, const int* __restrict__ pos_of,
                          const float* __restrict__ topk_w, float* __restrict__ out) {
    int idx = blockIdx.x * 256 + threadIdx.x;    // exactly T * (H/4)
    int t  = idx >> 9;
    int c4 = (idx & 511) << 2;
    int p0 = pos_of[t * 2], p1 = pos_of[t * 2 + 1];
    float w0 = topk_w[t * 2], w1 = topk_w[t * 2 + 1];
    u16x4 a = *(const u16x4*)(y + (size_t)p0 * HID + c4);
    u16x4 b = *(const u16x4*)(y + (size_t)p1 * HID + c4);
    f32x4 o;
#pragma unroll
    for (int q = 0; q < 4; ++q) o[q] = w0 * bf2f(a[q]) + w1 * bf2f(b[q]);
    *(f32x4*)(out + (size_t)t * HID + c4) = o;
    if (idx == 0) out[(size_t)T_TOK * HID] = 0.f;   // second output: zeros((1,))
}

__global__ void k_init(int* __restrict__ c) {
    if (threadIdx.x < 16) c[threadIdx.x] = 0;       // counts[8] + cursors[8]
}

// ================= fallback GEMM (round-1, fp32 B reg-staged) — used only if
// ws_size is too small for the bf16 weight cache =================
template<int KTOT, int NTOT, bool DUAL, bool GATHER>
__global__ __launch_bounds__(256) void k_gemm_fb(
    const u16* __restrict__ A,
    const float* __restrict__ Ball0,
    const float* __restrict__ Ball1,
    u16* __restrict__ C,
    const int* __restrict__ perm_tok,
    const int* __restrict__ pad_off)
{
    const int e    = blockIdx.z;
    const int base = pad_off[e];
    const int ne   = pad_off[e + 1] - base;
    const int m0   = blockIdx.y * BM;
    if (m0 >= ne) return;
    const int n0  = blockIdx.x * BN;
    const int tid = threadIdx.x;

    __shared__ u16 As[BM * BK];
    __shared__ u16 Bs0[BN * BK];
    __shared__ u16 Bs1[DUAL ? BN * BK : 8];
    __shared__ int tokS[BM];

    const float* B0 = Ball0 + (size_t)e * NTOT * KTOT;
    const float* B1 = DUAL ? (Ball1 + (size_t)e * NTOT * KTOT) : Ball0;

    if (GATHER) {
        if (tid < BM) tokS[tid] = perm_tok[base + m0 + tid];
        __syncthreads();
    }

    const int sr = tid >> 3;
    const int sc = tid & 7;
    const u16*   aRow[4];
    const float* b0Row[4];
    const float* b1Row[4];
    int dIdx[4];
#pragma unroll
    for (int i = 0; i < 4; ++i) {
        int r = sr + 32 * i;
        if (GATHER) aRow[i] = A + (size_t)tokS[r] * KTOT + sc * 8;
        else        aRow[i] = A + (size_t)(base + m0 + r) * KTOT + sc * 8;
        b0Row[i] = B0 + (size_t)(n0 + r) * KTOT + sc * 8;
        b1Row[i] = B1 + (size_t)(n0 + r) * KTOT + sc * 8;
        dIdx[i] = r * BK + ((sc ^ (sr & 7)) << 3);
    }

    const int lane = tid & 63;
    const int wid  = tid >> 6;
    const int wm   = (wid >> 1) * 64;
    const int wn   = (wid & 1) * 64;
    const int fr   = lane & 15;
    const int fk   = lane >> 4;
    const int x7   = fr & 7;

    f32x4 acc0[4][4], acc1[4][4];
    const f32x4 fz = {0.f, 0.f, 0.f, 0.f};
#pragma unroll
    for (int i = 0; i < 4; ++i)
#pragma unroll
        for (int j = 0; j < 4; ++j) { acc0[i][j] = fz; acc1[i][j] = fz; }

    for (int ks = 0; ks < KTOT / BK; ++ks) {
        short8 av[4], b0s[4], b1s[4];
#pragma unroll
        for (int i = 0; i < 4; ++i) {
            av[i] = *(const short8*)(aRow[i]);  aRow[i] += BK;
            f32x4 f0 = *(const f32x4*)(b0Row[i]);
            f32x4 f1 = *(const f32x4*)(b0Row[i] + 4);  b0Row[i] += BK;
#pragma unroll
            for (int q = 0; q < 4; ++q) { b0s[i][q] = (short)f2bf(f0[q]); b0s[i][q + 4] = (short)f2bf(f1[q]); }
            if (DUAL) {
                f32x4 g0 = *(const f32x4*)(b1Row[i]);
                f32x4 g1 = *(const f32x4*)(b1Row[i] + 4);  b1Row[i] += BK;
#pragma unroll
                for (int q = 0; q < 4; ++q) { b1s[i][q] = (short)f2bf(g0[q]); b1s[i][q + 4] = (short)f2bf(g1[q]); }
            }
        }
        __syncthreads();
#pragma unroll
        for (int i = 0; i < 4; ++i) {
            *(short8*)(&As[dIdx[i]])  = av[i];
            *(short8*)(&Bs0[dIdx[i]]) = b0s[i];
            if (DUAL) *(short8*)(&Bs1[dIdx[i]]) = b1s[i];
        }
        __syncthreads();
#pragma unroll
        for (int kk = 0; kk < 2; ++kk) {
            short8 af[4], b0f[4], b1f[4];
            const int ct = ((kk * 4 + fk) ^ x7) << 3;
#pragma unroll
            for (int i = 0; i < 4; ++i) af[i]  = *(const short8*)(&As[(wm + i * 16 + fr) * BK + ct]);
#pragma unroll
            for (int j = 0; j < 4; ++j) b0f[j] = *(const short8*)(&Bs0[(wn + j * 16 + fr) * BK + ct]);
            if (DUAL) {
#pragma unroll
                for (int j = 0; j < 4; ++j) b1f[j] = *(const short8*)(&Bs1[(wn + j * 16 + fr) * BK + ct]);
            }
#pragma unroll
            for (int i = 0; i < 4; ++i)
#pragma unroll
                for (int j = 0; j < 4; ++j) {
                    acc0[i][j] = __builtin_amdgcn_mfma_f32_16x16x32_bf16(af[i], b0f[j], acc0[i][j], 0, 0, 0);
                    if (DUAL)
                        acc1[i][j] = __builtin_amdgcn_mfma_f32_16x16x32_bf16(af[i], b1f[j], acc1[i][j], 0, 0, 0);
                }
        }
        __syncthreads();
    }

    const int er = (lane >> 4) * 4;
    const int ec = lane & 15;
#pragma unroll
    for (int i = 0; i < 4; ++i)
#pragma unroll
        for (int j = 0; j < 4; ++j)
#pragma unroll
            for (int r = 0; r < 4; ++r) {
                size_t prow = (size_t)(base + m0 + wm + i * 16 + er + r);
                int col = n0 + wn + j * 16 + ec;
                float v = acc0[i][j][r];
                float res;
                if (DUAL) {
                    float g3 = acc1[i][j][r];
                    res = v / (1.f + __expf(-v)) * g3;
                } else {
                    res = v;
                }
                C[prow * NTOT + col] = f2bf(res);
            }
}

extern "C" void kernel_launch(void* const* d_in, const int* in_sizes, int n_in,
                              void* d_out, int out_size, void* d_ws, size_t ws_size,
                              hipStream_t stream) {
    const float* x  = (const float*)d_in[0];
    const float* wr = (const float*)d_in[1];
    const float* w1 = (const float*)d_in[2];
    const float* w2 = (const float*)d_in[3];
    const float* w3 = (const float*)d_in[4];
    float* out = (float*)d_out;
    char* ws = (char*)d_ws;

    const size_t NEED = 474091648ull;

    if (ws_size >= NEED) {
        // ---- main path: bf16 weight cache + global_load_lds GEMMs ----
        u16*  xb  = (u16*)(ws);                          // 16,777,216
        u16*  wA  = (u16*)(ws + 16777216);               // 134,217,728 (w1b, later w2b)
        u16*  w3b = (u16*)(ws + 150994944);              // 134,217,728
        u16*  g1  = (u16*)(ws + 285212672);              // 75,497,472  (9216 x 4096), h in-place
        u16*  g3  = (u16*)(ws + 360710144);              // 75,497,472
        u16*  yb  = (u16*)(ws + 436207616);              // 37,748,736  (9216 x 2048)
        int*  perm_tok = (int*)(ws + 473956352);
        int*  pos_of   = (int*)(ws + 473993216);
        int*  topk_id  = (int*)(ws + 474025984);
        float* topk_w  = (float*)(ws + 474058752);
        int*  cnt      = (int*)(ws + 474091520);
        int*  counts   = cnt;
        int*  cursors  = cnt + 8;
        int*  pad_off  = cnt + 16;

        k_init<<<1, 64, 0, stream>>>(cnt);
        k_convert<<<2048, 256, 0, stream>>>(x, xb, (long)T_TOK * HID / 8);
        k_router<<<1024, 256, 0, stream>>>(x, wr, topk_id, topk_w, counts);
        k_scan<<<1, 256, 0, stream>>>(counts, pad_off, perm_tok);
        k_scatter<<<16, 256, 0, stream>>>(topk_id, cursors, pad_off, perm_tok, pos_of);

        const long WN8 = (long)NE * FFN_D * HID / 8;     // per weight tensor
        k_convert<<<4096, 256, 0, stream>>>(w1, wA, WN8);
        k_convert<<<4096, 256, 0, stream>>>(w3, w3b, WN8);

        k_gemm<HID, FFN_D, true><<<dim3(FFN_D / BN, 32, NE), 256, 0, stream>>>(
            xb, wA, g1, perm_tok, pad_off);
        k_gemm<HID, FFN_D, true><<<dim3(FFN_D / BN, 32, NE), 256, 0, stream>>>(
            xb, w3b, g3, perm_tok, pad_off);

        k_swiglu<<<2048, 256, 0, stream>>>(g1, g3, pad_off);

        k_convert<<<4096, 256, 0, stream>>>(w2, wA, WN8);  // reuse w1's slot
        k_gemm<FFN_D, HID, false><<<dim3(HID / BN, 32, NE), 256, 0, stream>>>(
            g1, wA, yb, perm_tok, pad_off);

        k_combine<<<8192, 256, 0, stream>>>(yb, pos_of, topk_w, out);
    } else {
        // ---- fallback: round-1 layout (needs ~130.2 MB) ----
        u16*  xb       = (u16*)(ws);
        u16*  hbuf     = (u16*)(ws + 16777216);
        u16*  ybuf     = (u16*)(ws + 92274688);
        int*  perm_tok = (int*)(ws + 130023424);
        int*  pos_of   = (int*)(ws + 130060288);
        int*  topk_id  = (int*)(ws + 130093056);
        float* topk_w  = (float*)(ws + 130125824);
        int*  cnt      = (int*)(ws + 130158592);
        int*  counts   = cnt;
        int*  cursors  = cnt + 8;
        int*  pad_off  = cnt + 16;

        k_init<<<1, 64, 0, stream>>>(cnt);
        k_convert<<<2048, 256, 0, stream>>>(x, xb, (long)T_TOK * HID / 8);
        k_router<<<1024, 256, 0, stream>>>(x, wr, topk_id, topk_w, counts);
        k_scan<<<1, 256, 0, stream>>>(counts, pad_off, perm_tok);
        k_scatter<<<16, 256, 0, stream>>>(topk_id, cursors, pad_off, perm_tok, pos_of);

        k_gemm_fb<HID, FFN_D, true, true><<<dim3(FFN_D / BN, 32, NE), 256, 0, stream>>>(
            xb, w1, w3, hbuf, perm_tok, pad_off);
        k_gemm_fb<FFN_D, HID, false, false><<<dim3(HID / BN, 32, NE), 256, 0, stream>>>(
            hbuf, w2, (const float*)nullptr, ybuf, perm_tok, pad_off);

        k_combine<<<8192, 256, 0, stream>>>(ybuf, pos_of, topk_w, out);
    }
}

// Round 3
// 1195.174 us; speedup vs baseline: 1.0822x; 1.0393x over previous
//
#include <hip/hip_runtime.h>
#include <hip/hip_bf16.h>
#include <stdint.h>

#define T_TOK 4096
#define HID   2048
#define FFN_D 4096
#define NE    8
#define BM    128
#define BN    128
#define BK    64

typedef __attribute__((ext_vector_type(8))) short  short8;
typedef __attribute__((ext_vector_type(4))) float  f32x4;
typedef __attribute__((ext_vector_type(4))) unsigned short u16x4;
typedef unsigned short u16;

__device__ __forceinline__ u16 f2bf(float f) {
    unsigned u = __float_as_uint(f);
    u += 0x7FFFu + ((u >> 16) & 1u);   // RNE
    return (u16)(u >> 16);
}
__device__ __forceinline__ float bf2f(u16 v) {
    return __uint_as_float(((unsigned)v) << 16);
}

// direct global->LDS, 16B per lane; LDS dest = wave-uniform base + lane*16
#define GLD16(g, l) __builtin_amdgcn_global_load_lds( \
    (const __attribute__((address_space(1))) unsigned int*)(g), \
    (__attribute__((address_space(3))) unsigned int*)(l), 16, 0, 0)

// ---------------- generic fp32 -> bf16 converter (grid-stride, x8 vectorized) ----
__global__ void k_convert(const float* __restrict__ s, u16* __restrict__ d, long n8) {
    for (long i = (long)blockIdx.x * 256 + threadIdx.x; i < n8; i += (long)gridDim.x * 256) {
        f32x4 a = *((const f32x4*)s + i * 2);
        f32x4 b = *((const f32x4*)s + i * 2 + 1);
        short8 o;
#pragma unroll
        for (int q = 0; q < 4; ++q) { o[q] = (short)f2bf(a[q]); o[q + 4] = (short)f2bf(b[q]); }
        *(short8*)(d + i * 8) = o;
    }
}

// ---------------- router (1 wave per token) ----------------
__global__ void k_router(const float* __restrict__ x, const float* __restrict__ wr,
                         int* __restrict__ topk_id, float* __restrict__ topk_w,
                         int* __restrict__ counts) {
    int lane = threadIdx.x & 63;
    int t = blockIdx.x * 4 + (threadIdx.x >> 6);
    const float* xr = x + (size_t)t * HID;
    float acc[8];
#pragma unroll
    for (int e = 0; e < 8; ++e) acc[e] = 0.f;
    for (int h = lane; h < HID; h += 64) {
        float xv = xr[h];
        f32x4 w0 = *(const f32x4*)(wr + h * 8);
        f32x4 w1 = *(const f32x4*)(wr + h * 8 + 4);
#pragma unroll
        for (int q = 0; q < 4; ++q) { acc[q] += xv * w0[q]; acc[4 + q] += xv * w1[q]; }
    }
#pragma unroll
    for (int e = 0; e < 8; ++e) {
        float v = acc[e];
#pragma unroll
        for (int s = 32; s > 0; s >>= 1) v += __shfl_xor(v, s);
        acc[e] = v;
    }
    if (lane == 0) {
        int i0 = 0; float l0 = acc[0];
#pragma unroll
        for (int e = 1; e < 8; ++e) if (acc[e] > l0) { l0 = acc[e]; i0 = e; }
        int i1 = -1; float l1 = -3.4e38f;
#pragma unroll
        for (int e = 0; e < 8; ++e) if (e != i0 && acc[e] > l1) { l1 = acc[e]; i1 = e; }
        float wA = 1.f / (1.f + expf(l1 - l0));   // top-2 softmax renorm, denom cancels
        topk_id[t * 2] = i0;  topk_id[t * 2 + 1] = i1;
        topk_w[t * 2] = wA;   topk_w[t * 2 + 1] = 1.f - wA;
        atomicAdd(&counts[i0], 1);
        atomicAdd(&counts[i1], 1);
    }
}

// ---------------- padded scan + fill ----------------
__global__ void k_scan(const int* __restrict__ counts, int* __restrict__ pad_off,
                       int* __restrict__ perm_tok) {
    __shared__ int sTot;
    if (threadIdx.x == 0) {
        int o = 0;
#pragma unroll
        for (int e = 0; e < 8; ++e) { pad_off[e] = o; o += ((counts[e] + BM - 1) / BM) * BM; }
        pad_off[8] = o; sTot = o;
    }
    __syncthreads();
    int tot = sTot;
    for (int i = threadIdx.x; i < tot; i += 256) perm_tok[i] = 0;  // filler = token 0
}

// ---------------- scatter tokens into expert lists ----------------
__global__ void k_scatter(const int* __restrict__ topk_id, int* __restrict__ cursors,
                          const int* __restrict__ pad_off, int* __restrict__ perm_tok,
                          int* __restrict__ pos_of) {
    int t = blockIdx.x * 256 + threadIdx.x;
    if (t >= T_TOK) return;
#pragma unroll
    for (int k = 0; k < 2; ++k) {
        int e = topk_id[t * 2 + k];
        int p = pad_off[e] + atomicAdd(&cursors[e], 1);
        perm_tok[p] = t;
        pos_of[t * 2 + k] = p;
    }
}

// =========== stage-1: dual-B GEMM + fused SwiGLU =================
// A [T,HID] bf16 gathered; B0=w1b, B1=w3b [E][FFN,HID] bf16; C=h [pad,FFN] bf16.
// T2 both-sides swizzle: linear LDS dest (global_load_lds), inverse-swizzled
// global source chunk (l&7)^(row&7), swizzled ds_read slot ct^(fr&7).
__global__ __launch_bounds__(256) void k_gemm_dual(
    const u16* __restrict__ A,
    const u16* __restrict__ B0all,
    const u16* __restrict__ B1all,
    u16* __restrict__ C,
    const int* __restrict__ perm_tok,
    const int* __restrict__ pad_off)
{
    const int m0 = blockIdx.y * BM;
    if (m0 >= pad_off[8]) return;
    int e = 0;
    while (pad_off[e + 1] <= m0) ++e;
    const int n0  = blockIdx.x * BN;
    const int tid = threadIdx.x;

    __shared__ u16 As[BM * BK];
    __shared__ u16 Bs0[BN * BK];
    __shared__ u16 Bs1[BN * BK];
    __shared__ int tokS[BM];

    const u16* B0 = B0all + (size_t)e * FFN_D * HID;
    const u16* B1 = B1all + (size_t)e * FFN_D * HID;

    if (tid < BM) tokS[tid] = perm_tok[m0 + tid];
    __syncthreads();

    const int w = tid >> 6, l = tid & 63;
    int aOff[4], bOff[4];
    u16 *aDst[4], *b0Dst[4], *b1Dst[4];
#pragma unroll
    for (int s = 0; s < 4; ++s) {
        int gs  = w * 4 + s;
        int row = gs * 8 + (l >> 3);
        int ch  = (l & 7) ^ (row & 7);              // inverse-swizzled source chunk
        aOff[s] = tokS[row] * HID + ch * 8;
        bOff[s] = (n0 + row) * HID + ch * 8;
        aDst[s]  = &As[gs * 512];                   // wave-uniform base
        b0Dst[s] = &Bs0[gs * 512];
        b1Dst[s] = &Bs1[gs * 512];
    }

    const int lane = tid & 63;
    const int wid  = tid >> 6;
    const int wm   = (wid >> 1) * 64;
    const int wn   = (wid & 1) * 64;
    const int fr   = lane & 15;
    const int fk   = lane >> 4;
    const int x7   = fr & 7;

    f32x4 acc0[4][4], acc1[4][4];
    const f32x4 fz = {0.f, 0.f, 0.f, 0.f};
#pragma unroll
    for (int i = 0; i < 4; ++i)
#pragma unroll
        for (int j = 0; j < 4; ++j) { acc0[i][j] = fz; acc1[i][j] = fz; }

    for (int ks = 0; ks < HID / BK; ++ks) {
        const int k0 = ks * BK;
        __syncthreads();                             // prev tile's reads done
#pragma unroll
        for (int s = 0; s < 4; ++s) {
            GLD16(A  + aOff[s] + k0, aDst[s]);
            GLD16(B0 + bOff[s] + k0, b0Dst[s]);
            GLD16(B1 + bOff[s] + k0, b1Dst[s]);
        }
        __syncthreads();                             // drain -> tile ready
#pragma unroll
        for (int kk = 0; kk < 2; ++kk) {
            short8 af[4], b0f[4], b1f[4];
            const int ct = ((kk * 4 + fk) ^ x7) << 3;   // swizzled read slot
#pragma unroll
            for (int i = 0; i < 4; ++i) af[i]  = *(const short8*)(&As[(wm + i * 16 + fr) * BK + ct]);
#pragma unroll
            for (int j = 0; j < 4; ++j) b0f[j] = *(const short8*)(&Bs0[(wn + j * 16 + fr) * BK + ct]);
#pragma unroll
            for (int j = 0; j < 4; ++j) b1f[j] = *(const short8*)(&Bs1[(wn + j * 16 + fr) * BK + ct]);
#pragma unroll
            for (int i = 0; i < 4; ++i)
#pragma unroll
                for (int j = 0; j < 4; ++j) {
                    acc0[i][j] = __builtin_amdgcn_mfma_f32_16x16x32_bf16(af[i], b0f[j], acc0[i][j], 0, 0, 0);
                    acc1[i][j] = __builtin_amdgcn_mfma_f32_16x16x32_bf16(af[i], b1f[j], acc1[i][j], 0, 0, 0);
                }
        }
    }

    // epilogue: h = silu(g1) * g3 ; C/D layout col=lane&15, row=(lane>>4)*4+reg
    const int er = (lane >> 4) * 4;
    const int ec = lane & 15;
#pragma unroll
    for (int i = 0; i < 4; ++i)
#pragma unroll
        for (int j = 0; j < 4; ++j)
#pragma unroll
            for (int r = 0; r < 4; ++r) {
                size_t prow = (size_t)(m0 + wm + i * 16 + er + r);
                int col = n0 + wn + j * 16 + ec;
                float v = acc0[i][j][r];
                float g3 = acc1[i][j][r];
                C[prow * FFN_D + col] = f2bf(v / (1.f + __expf(-v)) * g3);
            }
}

// =========== stage-2: single-B GEMM (h @ w2^T), same swizzle =================
__global__ __launch_bounds__(256) void k_gemm2(
    const u16* __restrict__ A,
    const u16* __restrict__ Ball,
    u16* __restrict__ C,
    const int* __restrict__ pad_off)
{
    const int m0 = blockIdx.y * BM;
    if (m0 >= pad_off[8]) return;
    int e = 0;
    while (pad_off[e + 1] <= m0) ++e;
    const int n0  = blockIdx.x * BN;
    const int tid = threadIdx.x;

    __shared__ u16 As[BM * BK];
    __shared__ u16 Bs[BN * BK];

    const u16* B = Ball + (size_t)e * HID * FFN_D;

    const int w = tid >> 6, l = tid & 63;
    int aOff[4], bOff[4];
    u16 *aDst[4], *bDst[4];
#pragma unroll
    for (int s = 0; s < 4; ++s) {
        int gs  = w * 4 + s;
        int row = gs * 8 + (l >> 3);
        int ch  = (l & 7) ^ (row & 7);
        aOff[s] = (m0 + row) * FFN_D + ch * 8;
        bOff[s] = (n0 + row) * FFN_D + ch * 8;
        aDst[s] = &As[gs * 512];
        bDst[s] = &Bs[gs * 512];
    }

    const int lane = tid & 63;
    const int wid  = tid >> 6;
    const int wm   = (wid >> 1) * 64;
    const int wn   = (wid & 1) * 64;
    const int fr   = lane & 15;
    const int fk   = lane >> 4;
    const int x7   = fr & 7;

    f32x4 acc[4][4];
    const f32x4 fz = {0.f, 0.f, 0.f, 0.f};
#pragma unroll
    for (int i = 0; i < 4; ++i)
#pragma unroll
        for (int j = 0; j < 4; ++j) acc[i][j] = fz;

    for (int ks = 0; ks < FFN_D / BK; ++ks) {
        const int k0 = ks * BK;
        __syncthreads();
#pragma unroll
        for (int s = 0; s < 4; ++s) {
            GLD16(A + aOff[s] + k0, aDst[s]);
            GLD16(B + bOff[s] + k0, bDst[s]);
        }
        __syncthreads();
#pragma unroll
        for (int kk = 0; kk < 2; ++kk) {
            short8 af[4], bf[4];
            const int ct = ((kk * 4 + fk) ^ x7) << 3;
#pragma unroll
            for (int i = 0; i < 4; ++i) af[i] = *(const short8*)(&As[(wm + i * 16 + fr) * BK + ct]);
#pragma unroll
            for (int j = 0; j < 4; ++j) bf[j] = *(const short8*)(&Bs[(wn + j * 16 + fr) * BK + ct]);
#pragma unroll
            for (int i = 0; i < 4; ++i)
#pragma unroll
                for (int j = 0; j < 4; ++j)
                    acc[i][j] = __builtin_amdgcn_mfma_f32_16x16x32_bf16(af[i], bf[j], acc[i][j], 0, 0, 0);
        }
    }

    const int er = (lane >> 4) * 4;
    const int ec = lane & 15;
#pragma unroll
    for (int i = 0; i < 4; ++i)
#pragma unroll
        for (int j = 0; j < 4; ++j)
#pragma unroll
            for (int r = 0; r < 4; ++r) {
                size_t prow = (size_t)(m0 + wm + i * 16 + er + r);
                int col = n0 + wn + j * 16 + ec;
                C[prow * HID + col] = f2bf(acc[i][j][r]);
            }
}

// ---------------- weighted combine ----------------
__global__ void k_combine(const u16* __restrict__ y, const int* __restrict__ pos_of,
                          const float* __restrict__ topk_w, float* __restrict__ out) {
    int idx = blockIdx.x * 256 + threadIdx.x;    // exactly T * (H/4)
    int t  = idx >> 9;
    int c4 = (idx & 511) << 2;
    int p0 = pos_of[t * 2], p1 = pos_of[t * 2 + 1];
    float w0 = topk_w[t * 2], w1 = topk_w[t * 2 + 1];
    u16x4 a = *(const u16x4*)(y + (size_t)p0 * HID + c4);
    u16x4 b = *(const u16x4*)(y + (size_t)p1 * HID + c4);
    f32x4 o;
#pragma unroll
    for (int q = 0; q < 4; ++q) o[q] = w0 * bf2f(a[q]) + w1 * bf2f(b[q]);
    *(f32x4*)(out + (size_t)t * HID + c4) = o;
    if (idx == 0) out[(size_t)T_TOK * HID] = 0.f;   // second output: zeros((1,))
}

__global__ void k_init(int* __restrict__ c) {
    if (threadIdx.x < 16) c[threadIdx.x] = 0;       // counts[8] + cursors[8]
}

// ================= fallback GEMM (fp32 B reg-staged) — only if ws too small ======
template<int KTOT, int NTOT, bool DUAL, bool GATHER>
__global__ __launch_bounds__(256) void k_gemm_fb(
    const u16* __restrict__ A,
    const float* __restrict__ Ball0,
    const float* __restrict__ Ball1,
    u16* __restrict__ C,
    const int* __restrict__ perm_tok,
    const int* __restrict__ pad_off)
{
    const int e    = blockIdx.z;
    const int base = pad_off[e];
    const int ne   = pad_off[e + 1] - base;
    const int m0   = blockIdx.y * BM;
    if (m0 >= ne) return;
    const int n0  = blockIdx.x * BN;
    const int tid = threadIdx.x;

    __shared__ u16 As[BM * BK];
    __shared__ u16 Bs0[BN * BK];
    __shared__ u16 Bs1[DUAL ? BN * BK : 8];
    __shared__ int tokS[BM];

    const float* B0 = Ball0 + (size_t)e * NTOT * KTOT;
    const float* B1 = DUAL ? (Ball1 + (size_t)e * NTOT * KTOT) : Ball0;

    if (GATHER) {
        if (tid < BM) tokS[tid] = perm_tok[base + m0 + tid];
        __syncthreads();
    }

    const int sr = tid >> 3;
    const int sc = tid & 7;
    const u16*   aRow[4];
    const float* b0Row[4];
    const float* b1Row[4];
    int dIdx[4];
#pragma unroll
    for (int i = 0; i < 4; ++i) {
        int r = sr + 32 * i;
        if (GATHER) aRow[i] = A + (size_t)tokS[r] * KTOT + sc * 8;
        else        aRow[i] = A + (size_t)(base + m0 + r) * KTOT + sc * 8;
        b0Row[i] = B0 + (size_t)(n0 + r) * KTOT + sc * 8;
        b1Row[i] = B1 + (size_t)(n0 + r) * KTOT + sc * 8;
        dIdx[i] = r * BK + ((sc ^ (sr & 7)) << 3);
    }

    const int lane = tid & 63;
    const int wid  = tid >> 6;
    const int wm   = (wid >> 1) * 64;
    const int wn   = (wid & 1) * 64;
    const int fr   = lane & 15;
    const int fk   = lane >> 4;
    const int x7   = fr & 7;

    f32x4 acc0[4][4], acc1[4][4];
    const f32x4 fz = {0.f, 0.f, 0.f, 0.f};
#pragma unroll
    for (int i = 0; i < 4; ++i)
#pragma unroll
        for (int j = 0; j < 4; ++j) { acc0[i][j] = fz; acc1[i][j] = fz; }

    for (int ks = 0; ks < KTOT / BK; ++ks) {
        short8 av[4], b0s[4], b1s[4];
#pragma unroll
        for (int i = 0; i < 4; ++i) {
            av[i] = *(const short8*)(aRow[i]);  aRow[i] += BK;
            f32x4 f0 = *(const f32x4*)(b0Row[i]);
            f32x4 f1 = *(const f32x4*)(b0Row[i] + 4);  b0Row[i] += BK;
#pragma unroll
            for (int q = 0; q < 4; ++q) { b0s[i][q] = (short)f2bf(f0[q]); b0s[i][q + 4] = (short)f2bf(f1[q]); }
            if (DUAL) {
                f32x4 g0 = *(const f32x4*)(b1Row[i]);
                f32x4 g1 = *(const f32x4*)(b1Row[i] + 4);  b1Row[i] += BK;
#pragma unroll
                for (int q = 0; q < 4; ++q) { b1s[i][q] = (short)f2bf(g0[q]); b1s[i][q + 4] = (short)f2bf(g1[q]); }
            }
        }
        __syncthreads();
#pragma unroll
        for (int i = 0; i < 4; ++i) {
            *(short8*)(&As[dIdx[i]])  = av[i];
            *(short8*)(&Bs0[dIdx[i]]) = b0s[i];
            if (DUAL) *(short8*)(&Bs1[dIdx[i]]) = b1s[i];
        }
        __syncthreads();
#pragma unroll
        for (int kk = 0; kk < 2; ++kk) {
            short8 af[4], b0f[4], b1f[4];
            const int ct = ((kk * 4 + fk) ^ x7) << 3;
#pragma unroll
            for (int i = 0; i < 4; ++i) af[i]  = *(const short8*)(&As[(wm + i * 16 + fr) * BK + ct]);
#pragma unroll
            for (int j = 0; j < 4; ++j) b0f[j] = *(const short8*)(&Bs0[(wn + j * 16 + fr) * BK + ct]);
            if (DUAL) {
#pragma unroll
                for (int j = 0; j < 4; ++j) b1f[j] = *(const short8*)(&Bs1[(wn + j * 16 + fr) * BK + ct]);
            }
#pragma unroll
            for (int i = 0; i < 4; ++i)
#pragma unroll
                for (int j = 0; j < 4; ++j) {
                    acc0[i][j] = __builtin_amdgcn_mfma_f32_16x16x32_bf16(af[i], b0f[j], acc0[i][j], 0, 0, 0);
                    if (DUAL)
                        acc1[i][j] = __builtin_amdgcn_mfma_f32_16x16x32_bf16(af[i], b1f[j], acc1[i][j], 0, 0, 0);
                }
        }
        __syncthreads();
    }

    const int er = (lane >> 4) * 4;
    const int ec = lane & 15;
#pragma unroll
    for (int i = 0; i < 4; ++i)
#pragma unroll
        for (int j = 0; j < 4; ++j)
#pragma unroll
            for (int r = 0; r < 4; ++r) {
                size_t prow = (size_t)(base + m0 + wm + i * 16 + er + r);
                int col = n0 + wn + j * 16 + ec;
                float v = acc0[i][j][r];
                float res;
                if (DUAL) {
                    float g3 = acc1[i][j][r];
                    res = v / (1.f + __expf(-v)) * g3;
                } else {
                    res = v;
                }
                C[prow * NTOT + col] = f2bf(res);
            }
}

extern "C" void kernel_launch(void* const* d_in, const int* in_sizes, int n_in,
                              void* d_out, int out_size, void* d_ws, size_t ws_size,
                              hipStream_t stream) {
    const float* x  = (const float*)d_in[0];
    const float* wr = (const float*)d_in[1];
    const float* w1 = (const float*)d_in[2];
    const float* w2 = (const float*)d_in[3];
    const float* w3 = (const float*)d_in[4];
    float* out = (float*)d_out;
    char* ws = (char*)d_ws;

    const size_t NEED = 398594176ull;

    if (ws_size >= NEED) {
        // ---- main path: bf16 weight cache + dual-B fused stage-1 ----
        u16*  xb  = (u16*)(ws);                          // 16,777,216
        u16*  wA  = (u16*)(ws + 16777216);               // 134,217,728 (w1b, later w2b)
        u16*  w3b = (u16*)(ws + 150994944);              // 134,217,728
        u16*  hb  = (u16*)(ws + 285212672);              // 75,497,472  (9216 x 4096)
        u16*  yb  = (u16*)(ws + 360710144);              // 37,748,736  (9216 x 2048)
        int*  perm_tok = (int*)(ws + 398458880);
        int*  pos_of   = (int*)(ws + 398495744);
        int*  topk_id  = (int*)(ws + 398528512);
        float* topk_w  = (float*)(ws + 398561280);
        int*  cnt      = (int*)(ws + 398594048);
        int*  counts   = cnt;
        int*  cursors  = cnt + 8;
        int*  pad_off  = cnt + 16;

        k_init<<<1, 64, 0, stream>>>(cnt);
        k_convert<<<2048, 256, 0, stream>>>(x, xb, (long)T_TOK * HID / 8);
        k_router<<<1024, 256, 0, stream>>>(x, wr, topk_id, topk_w, counts);
        k_scan<<<1, 256, 0, stream>>>(counts, pad_off, perm_tok);
        k_scatter<<<16, 256, 0, stream>>>(topk_id, cursors, pad_off, perm_tok, pos_of);

        const long WN8 = (long)NE * FFN_D * HID / 8;
        k_convert<<<4096, 256, 0, stream>>>(w1, wA, WN8);
        k_convert<<<4096, 256, 0, stream>>>(w3, w3b, WN8);

        // stage 1: h = silu(x@w1^T) * (x@w3^T), one dispatch, flat 72 m-blocks
        k_gemm_dual<<<dim3(FFN_D / BN, 72), 256, 0, stream>>>(
            xb, wA, w3b, hb, perm_tok, pad_off);

        k_convert<<<4096, 256, 0, stream>>>(w2, wA, WN8);  // reuse w1's slot

        // stage 2: y = h @ w2^T
        k_gemm2<<<dim3(HID / BN, 72), 256, 0, stream>>>(hb, wA, yb, pad_off);

        k_combine<<<8192, 256, 0, stream>>>(yb, pos_of, topk_w, out);
    } else {
        // ---- fallback: fp32-weight reg-staged path (~130.2 MB) ----
        u16*  xb       = (u16*)(ws);
        u16*  hbuf     = (u16*)(ws + 16777216);
        u16*  ybuf     = (u16*)(ws + 92274688);
        int*  perm_tok = (int*)(ws + 130023424);
        int*  pos_of   = (int*)(ws + 130060288);
        int*  topk_id  = (int*)(ws + 130093056);
        float* topk_w  = (float*)(ws + 130125824);
        int*  cnt      = (int*)(ws + 130158592);
        int*  counts   = cnt;
        int*  cursors  = cnt + 8;
        int*  pad_off  = cnt + 16;

        k_init<<<1, 64, 0, stream>>>(cnt);
        k_convert<<<2048, 256, 0, stream>>>(x, xb, (long)T_TOK * HID / 8);
        k_router<<<1024, 256, 0, stream>>>(x, wr, topk_id, topk_w, counts);
        k_scan<<<1, 256, 0, stream>>>(counts, pad_off, perm_tok);
        k_scatter<<<16, 256, 0, stream>>>(topk_id, cursors, pad_off, perm_tok, pos_of);

        k_gemm_fb<HID, FFN_D, true, true><<<dim3(FFN_D / BN, 32, NE), 256, 0, stream>>>(
            xb, w1, w3, hbuf, perm_tok, pad_off);
        k_gemm_fb<FFN_D, HID, false, false><<<dim3(HID / BN, 32, NE), 256, 0, stream>>>(
            hbuf, w2, (const float*)nullptr, ybuf, perm_tok, pad_off);

        k_combine<<<8192, 256, 0, stream>>>(ybuf, pos_of, topk_w, out);
    }
}

// Round 4
// 1154.910 us; speedup vs baseline: 1.1199x; 1.0349x over previous
//
#include <hip/hip_runtime.h>
#include <hip/hip_bf16.h>
#include <stdint.h>

#define T_TOK 4096
#define HID   2048
#define FFN_D 4096
#define NE    8
#define BM    128
#define BN    128

typedef __attribute__((ext_vector_type(8))) short  short8;
typedef __attribute__((ext_vector_type(4))) float  f32x4;
typedef __attribute__((ext_vector_type(4))) unsigned short u16x4;
typedef unsigned short u16;

__device__ __forceinline__ u16 f2bf(float f) {
    unsigned u = __float_as_uint(f);
    u += 0x7FFFu + ((u >> 16) & 1u);   // RNE
    return (u16)(u >> 16);
}
__device__ __forceinline__ float bf2f(u16 v) {
    return __uint_as_float(((unsigned)v) << 16);
}

// direct global->LDS, 16B per lane; LDS dest = wave-uniform base + lane*16
#define GLD16(g, l) __builtin_amdgcn_global_load_lds( \
    (const __attribute__((address_space(1))) unsigned int*)(g), \
    (__attribute__((address_space(3))) unsigned int*)(l), 16, 0, 0)

// ---------------- generic fp32 -> bf16 converter (grid-stride, x8 vectorized) ----
__global__ void k_convert(const float* __restrict__ s, u16* __restrict__ d, long n8) {
    for (long i = (long)blockIdx.x * 256 + threadIdx.x; i < n8; i += (long)gridDim.x * 256) {
        f32x4 a = *((const f32x4*)s + i * 2);
        f32x4 b = *((const f32x4*)s + i * 2 + 1);
        short8 o;
#pragma unroll
        for (int q = 0; q < 4; ++q) { o[q] = (short)f2bf(a[q]); o[q + 4] = (short)f2bf(b[q]); }
        *(short8*)(d + i * 8) = o;
    }
}

// ---------------- router (1 wave per token) ----------------
__global__ void k_router(const float* __restrict__ x, const float* __restrict__ wr,
                         int* __restrict__ topk_id, float* __restrict__ topk_w,
                         int* __restrict__ counts) {
    int lane = threadIdx.x & 63;
    int t = blockIdx.x * 4 + (threadIdx.x >> 6);
    const float* xr = x + (size_t)t * HID;
    float acc[8];
#pragma unroll
    for (int e = 0; e < 8; ++e) acc[e] = 0.f;
    for (int h = lane; h < HID; h += 64) {
        float xv = xr[h];
        f32x4 w0 = *(const f32x4*)(wr + h * 8);
        f32x4 w1 = *(const f32x4*)(wr + h * 8 + 4);
#pragma unroll
        for (int q = 0; q < 4; ++q) { acc[q] += xv * w0[q]; acc[4 + q] += xv * w1[q]; }
    }
#pragma unroll
    for (int e = 0; e < 8; ++e) {
        float v = acc[e];
#pragma unroll
        for (int s = 32; s > 0; s >>= 1) v += __shfl_xor(v, s);
        acc[e] = v;
    }
    if (lane == 0) {
        int i0 = 0; float l0 = acc[0];
#pragma unroll
        for (int e = 1; e < 8; ++e) if (acc[e] > l0) { l0 = acc[e]; i0 = e; }
        int i1 = -1; float l1 = -3.4e38f;
#pragma unroll
        for (int e = 0; e < 8; ++e) if (e != i0 && acc[e] > l1) { l1 = acc[e]; i1 = e; }
        float wA = 1.f / (1.f + expf(l1 - l0));   // top-2 softmax renorm, denom cancels
        topk_id[t * 2] = i0;  topk_id[t * 2 + 1] = i1;
        topk_w[t * 2] = wA;   topk_w[t * 2 + 1] = 1.f - wA;
        atomicAdd(&counts[i0], 1);
        atomicAdd(&counts[i1], 1);
    }
}

// ---------------- padded scan + fill ----------------
__global__ void k_scan(const int* __restrict__ counts, int* __restrict__ pad_off,
                       int* __restrict__ perm_tok) {
    __shared__ int sTot;
    if (threadIdx.x == 0) {
        int o = 0;
#pragma unroll
        for (int e = 0; e < 8; ++e) { pad_off[e] = o; o += ((counts[e] + BM - 1) / BM) * BM; }
        pad_off[8] = o; sTot = o;
    }
    __syncthreads();
    int tot = sTot;
    for (int i = threadIdx.x; i < tot; i += 256) perm_tok[i] = 0;  // filler = token 0
}

// ---------------- scatter tokens into expert lists ----------------
__global__ void k_scatter(const int* __restrict__ topk_id, int* __restrict__ cursors,
                          const int* __restrict__ pad_off, int* __restrict__ perm_tok,
                          int* __restrict__ pos_of) {
    int t = blockIdx.x * 256 + threadIdx.x;
    if (t >= T_TOK) return;
#pragma unroll
    for (int k = 0; k < 2; ++k) {
        int e = topk_id[t * 2 + k];
        int p = pad_off[e] + atomicAdd(&cursors[e], 1);
        perm_tok[p] = t;
        pos_of[t * 2 + k] = p;
    }
}

// =========== unified 2-phase double-buffered MFMA GEMM ======================
// A [rows,KTOT] bf16 (opt. gathered), B [NTOT,KTOT] bf16/expert, C [pad,NTOT] bf16.
// - T3-minimum pipeline: STAGE(next buf) issued before compute(cur); the
//   __syncthreads() at loop top drains vmcnt(0) -> one tile of loads in flight
//   overlaps one tile of compute.
// - T2 both-sides swizzle at 16B granularity, generic in BK:
//   phys_chunk = logical_chunk ^ (((row*CH)>>3)&(CH-1))  (CH = BK/8)
// - T1 XCD swizzle: each XCD owns NB/8 contiguous n-columns, m-major inside.
template<int KTOT, int NTOT, int BKt, bool DUAL, bool GATHER>
__global__ __launch_bounds__(256) void k_gemm_t(
    const u16* __restrict__ A,
    const u16* __restrict__ B0all,
    const u16* __restrict__ B1all,
    u16* __restrict__ C,
    const int* __restrict__ perm_tok,
    const int* __restrict__ pad_off)
{
    constexpr int NB   = NTOT / BN;        // n-blocks
    constexpr int CPX  = NB / 8;           // n-cols per XCD
    constexpr int CH   = BKt / 8;          // 16B chunks per row
    constexpr int RPS  = 512 / BKt;        // rows per 1KB segment
    constexpr int SGW  = (BM * BKt) / 512 / 4;  // segments per wave per buffer
    constexpr int TILE = BM * BKt;         // u16 elements per buffer
    constexpr int NK   = KTOT / BKt;

    const int bid = blockIdx.x;
    const int xcd = bid & 7;
    const int i   = bid >> 3;
    const int m0  = (i / CPX) * BM;
    if (m0 >= pad_off[8]) return;
    const int n0  = (xcd * CPX + (i % CPX)) * BN;

    int e = 0;
    while (pad_off[e + 1] <= m0) ++e;

    __shared__ u16 As[2 * TILE];
    __shared__ u16 Bs0[2 * TILE];
    __shared__ u16 Bs1[DUAL ? 2 * TILE : 8];
    __shared__ int tokS[GATHER ? BM : 8];

    const int tid = threadIdx.x;
    if (GATHER) {
        if (tid < BM) tokS[tid] = perm_tok[m0 + tid];
        __syncthreads();
    }

    const u16* B0 = B0all + (size_t)e * NTOT * KTOT;
    const u16* B1 = DUAL ? (B1all + (size_t)e * NTOT * KTOT) : B0all;

    const int w = tid >> 6, l = tid & 63;
    int aOff[SGW], bOff[SGW], dOff[SGW];
#pragma unroll
    for (int s = 0; s < SGW; ++s) {
        int seg = w * SGW + s;
        int row = seg * RPS + l / CH;
        int c   = l % CH;
        int f   = ((row * CH) >> 3) & (CH - 1);
        int sl  = c ^ f;                    // inverse-swizzled source chunk
        int arow = GATHER ? tokS[row] : (m0 + row);
        aOff[s] = arow * KTOT + sl * 8;
        bOff[s] = (n0 + row) * KTOT + sl * 8;
        dOff[s] = seg * 512;                // wave-uniform LDS base (elements)
    }

    const int wm = (w >> 1) * 64;
    const int wn = (w & 1) * 64;
    const int fr = l & 15;
    const int fk = l >> 4;

    f32x4 acc0[4][4], acc1[4][4];
    const f32x4 fz = {0.f, 0.f, 0.f, 0.f};
#pragma unroll
    for (int ii = 0; ii < 4; ++ii)
#pragma unroll
        for (int jj = 0; jj < 4; ++jj) { acc0[ii][jj] = fz; acc1[ii][jj] = fz; }

    // prologue: stage first tile into buffer 0
    {
#pragma unroll
        for (int s = 0; s < SGW; ++s) {
            GLD16(A  + aOff[s], As  + dOff[s]);
            GLD16(B0 + bOff[s], Bs0 + dOff[s]);
            if (DUAL) GLD16(B1 + bOff[s], Bs1 + dOff[s]);
        }
    }

    for (int ks = 0; ks < NK; ++ks) {
        __syncthreads();                     // drains vmcnt(0): buf[ks&1] ready;
                                             // also: prev compute done -> nxt writable
        if (ks + 1 < NK) {
            const int k0 = (ks + 1) * BKt;
            u16* aB  = As  + ((ks + 1) & 1) * TILE;
            u16* b0B = Bs0 + ((ks + 1) & 1) * TILE;
            u16* b1B = Bs1 + ((ks + 1) & 1) * TILE;
#pragma unroll
            for (int s = 0; s < SGW; ++s) {
                GLD16(A  + aOff[s] + k0, aB  + dOff[s]);
                GLD16(B0 + bOff[s] + k0, b0B + dOff[s]);
                if (DUAL) GLD16(B1 + bOff[s] + k0, b1B + dOff[s]);
            }
        }
        const u16* aB  = As  + (ks & 1) * TILE;
        const u16* b0B = Bs0 + (ks & 1) * TILE;
        const u16* b1B = Bs1 + (ks & 1) * TILE;
#pragma unroll
        for (int kk = 0; kk < BKt / 32; ++kk) {
            short8 af[4], b0f[4], b1f[4];
#pragma unroll
            for (int ii = 0; ii < 4; ++ii) {
                int row = wm + ii * 16 + fr;
                int f   = ((row * CH) >> 3) & (CH - 1);
                int pc  = (kk * 4 + fk) ^ f;
                af[ii] = *(const short8*)(aB + row * BKt + pc * 8);
            }
#pragma unroll
            for (int jj = 0; jj < 4; ++jj) {
                int row = wn + jj * 16 + fr;
                int f   = ((row * CH) >> 3) & (CH - 1);
                int pc  = (kk * 4 + fk) ^ f;
                b0f[jj] = *(const short8*)(b0B + row * BKt + pc * 8);
                if (DUAL) b1f[jj] = *(const short8*)(b1B + row * BKt + pc * 8);
            }
#pragma unroll
            for (int ii = 0; ii < 4; ++ii)
#pragma unroll
                for (int jj = 0; jj < 4; ++jj) {
                    acc0[ii][jj] = __builtin_amdgcn_mfma_f32_16x16x32_bf16(af[ii], b0f[jj], acc0[ii][jj], 0, 0, 0);
                    if (DUAL)
                        acc1[ii][jj] = __builtin_amdgcn_mfma_f32_16x16x32_bf16(af[ii], b1f[jj], acc1[ii][jj], 0, 0, 0);
                }
        }
    }

    // epilogue: C/D layout col=lane&15, row=(lane>>4)*4+reg; DUAL -> SwiGLU fuse
    const int er = (l >> 4) * 4;
    const int ec = l & 15;
#pragma unroll
    for (int ii = 0; ii < 4; ++ii)
#pragma unroll
        for (int jj = 0; jj < 4; ++jj)
#pragma unroll
            for (int r = 0; r < 4; ++r) {
                size_t prow = (size_t)(m0 + wm + ii * 16 + er + r);
                int col = n0 + wn + jj * 16 + ec;
                float v = acc0[ii][jj][r];
                float res;
                if (DUAL) {
                    float g3 = acc1[ii][jj][r];
                    res = v / (1.f + __expf(-v)) * g3;   // silu(g1)*g3
                } else {
                    res = v;
                }
                C[prow * NTOT + col] = f2bf(res);
            }
}

// ---------------- weighted combine ----------------
__global__ void k_combine(const u16* __restrict__ y, const int* __restrict__ pos_of,
                          const float* __restrict__ topk_w, float* __restrict__ out) {
    int idx = blockIdx.x * 256 + threadIdx.x;    // exactly T * (H/4)
    int t  = idx >> 9;
    int c4 = (idx & 511) << 2;
    int p0 = pos_of[t * 2], p1 = pos_of[t * 2 + 1];
    float w0 = topk_w[t * 2], w1 = topk_w[t * 2 + 1];
    u16x4 a = *(const u16x4*)(y + (size_t)p0 * HID + c4);
    u16x4 b = *(const u16x4*)(y + (size_t)p1 * HID + c4);
    f32x4 o;
#pragma unroll
    for (int q = 0; q < 4; ++q) o[q] = w0 * bf2f(a[q]) + w1 * bf2f(b[q]);
    *(f32x4*)(out + (size_t)t * HID + c4) = o;
    if (idx == 0) out[(size_t)T_TOK * HID] = 0.f;   // second output: zeros((1,))
}

__global__ void k_init(int* __restrict__ c) {
    if (threadIdx.x < 16) c[threadIdx.x] = 0;       // counts[8] + cursors[8]
}

// ================= fallback GEMM (fp32 B reg-staged) — only if ws too small ======
template<int KTOT, int NTOT, bool DUAL, bool GATHER>
__global__ __launch_bounds__(256) void k_gemm_fb(
    const u16* __restrict__ A,
    const float* __restrict__ Ball0,
    const float* __restrict__ Ball1,
    u16* __restrict__ C,
    const int* __restrict__ perm_tok,
    const int* __restrict__ pad_off)
{
    const int e    = blockIdx.z;
    const int base = pad_off[e];
    const int ne   = pad_off[e + 1] - base;
    const int m0   = blockIdx.y * BM;
    if (m0 >= ne) return;
    const int n0  = blockIdx.x * BN;
    const int tid = threadIdx.x;
    const int BK = 64;

    __shared__ u16 As[BM * 64];
    __shared__ u16 Bs0[BN * 64];
    __shared__ u16 Bs1[DUAL ? BN * 64 : 8];
    __shared__ int tokS[BM];

    const float* B0 = Ball0 + (size_t)e * NTOT * KTOT;
    const float* B1 = DUAL ? (Ball1 + (size_t)e * NTOT * KTOT) : Ball0;

    if (GATHER) {
        if (tid < BM) tokS[tid] = perm_tok[base + m0 + tid];
        __syncthreads();
    }

    const int sr = tid >> 3;
    const int sc = tid & 7;
    const u16*   aRow[4];
    const float* b0Row[4];
    const float* b1Row[4];
    int dIdx[4];
#pragma unroll
    for (int i = 0; i < 4; ++i) {
        int r = sr + 32 * i;
        if (GATHER) aRow[i] = A + (size_t)tokS[r] * KTOT + sc * 8;
        else        aRow[i] = A + (size_t)(base + m0 + r) * KTOT + sc * 8;
        b0Row[i] = B0 + (size_t)(n0 + r) * KTOT + sc * 8;
        b1Row[i] = B1 + (size_t)(n0 + r) * KTOT + sc * 8;
        dIdx[i] = r * BK + ((sc ^ (sr & 7)) << 3);
    }

    const int lane = tid & 63;
    const int wid  = tid >> 6;
    const int wm   = (wid >> 1) * 64;
    const int wn   = (wid & 1) * 64;
    const int fr   = lane & 15;
    const int fk   = lane >> 4;
    const int x7   = fr & 7;

    f32x4 acc0[4][4], acc1[4][4];
    const f32x4 fz = {0.f, 0.f, 0.f, 0.f};
#pragma unroll
    for (int i = 0; i < 4; ++i)
#pragma unroll
        for (int j = 0; j < 4; ++j) { acc0[i][j] = fz; acc1[i][j] = fz; }

    for (int ks = 0; ks < KTOT / BK; ++ks) {
        short8 av[4], b0s[4], b1s[4];
#pragma unroll
        for (int i = 0; i < 4; ++i) {
            av[i] = *(const short8*)(aRow[i]);  aRow[i] += BK;
            f32x4 f0 = *(const f32x4*)(b0Row[i]);
            f32x4 f1 = *(const f32x4*)(b0Row[i] + 4);  b0Row[i] += BK;
#pragma unroll
            for (int q = 0; q < 4; ++q) { b0s[i][q] = (short)f2bf(f0[q]); b0s[i][q + 4] = (short)f2bf(f1[q]); }
            if (DUAL) {
                f32x4 g0 = *(const f32x4*)(b1Row[i]);
                f32x4 g1 = *(const f32x4*)(b1Row[i] + 4);  b1Row[i] += BK;
#pragma unroll
                for (int q = 0; q < 4; ++q) { b1s[i][q] = (short)f2bf(g0[q]); b1s[i][q + 4] = (short)f2bf(g1[q]); }
            }
        }
        __syncthreads();
#pragma unroll
        for (int i = 0; i < 4; ++i) {
            *(short8*)(&As[dIdx[i]])  = av[i];
            *(short8*)(&Bs0[dIdx[i]]) = b0s[i];
            if (DUAL) *(short8*)(&Bs1[dIdx[i]]) = b1s[i];
        }
        __syncthreads();
#pragma unroll
        for (int kk = 0; kk < 2; ++kk) {
            short8 af[4], b0f[4], b1f[4];
            const int ct = ((kk * 4 + fk) ^ x7) << 3;
#pragma unroll
            for (int i = 0; i < 4; ++i) af[i]  = *(const short8*)(&As[(wm + i * 16 + fr) * BK + ct]);
#pragma unroll
            for (int j = 0; j < 4; ++j) b0f[j] = *(const short8*)(&Bs0[(wn + j * 16 + fr) * BK + ct]);
            if (DUAL) {
#pragma unroll
                for (int j = 0; j < 4; ++j) b1f[j] = *(const short8*)(&Bs1[(wn + j * 16 + fr) * BK + ct]);
            }
#pragma unroll
            for (int i = 0; i < 4; ++i)
#pragma unroll
                for (int j = 0; j < 4; ++j) {
                    acc0[i][j] = __builtin_amdgcn_mfma_f32_16x16x32_bf16(af[i], b0f[j], acc0[i][j], 0, 0, 0);
                    if (DUAL)
                        acc1[i][j] = __builtin_amdgcn_mfma_f32_16x16x32_bf16(af[i], b1f[j], acc1[i][j], 0, 0, 0);
                }
        }
        __syncthreads();
    }

    const int er = (lane >> 4) * 4;
    const int ec = lane & 15;
#pragma unroll
    for (int i = 0; i < 4; ++i)
#pragma unroll
        for (int j = 0; j < 4; ++j)
#pragma unroll
            for (int r = 0; r < 4; ++r) {
                size_t prow = (size_t)(base + m0 + wm + i * 16 + er + r);
                int col = n0 + wn + j * 16 + ec;
                float v = acc0[i][j][r];
                float res;
                if (DUAL) {
                    float g3 = acc1[i][j][r];
                    res = v / (1.f + __expf(-v)) * g3;
                } else {
                    res = v;
                }
                C[prow * NTOT + col] = f2bf(res);
            }
}

extern "C" void kernel_launch(void* const* d_in, const int* in_sizes, int n_in,
                              void* d_out, int out_size, void* d_ws, size_t ws_size,
                              hipStream_t stream) {
    const float* x  = (const float*)d_in[0];
    const float* wr = (const float*)d_in[1];
    const float* w1 = (const float*)d_in[2];
    const float* w2 = (const float*)d_in[3];
    const float* w3 = (const float*)d_in[4];
    float* out = (float*)d_out;
    char* ws = (char*)d_ws;

    const size_t NEED = 398594176ull;

    if (ws_size >= NEED) {
        // ---- main path: bf16 weight cache + 2-phase pipelined GEMMs ----
        u16*  xb  = (u16*)(ws);                          // 16,777,216
        u16*  wA  = (u16*)(ws + 16777216);               // 134,217,728 (w1b, later w2b)
        u16*  w3b = (u16*)(ws + 150994944);              // 134,217,728
        u16*  hb  = (u16*)(ws + 285212672);              // 75,497,472  (9216 x 4096)
        u16*  yb  = (u16*)(ws + 360710144);              // 37,748,736  (9216 x 2048)
        int*  perm_tok = (int*)(ws + 398458880);
        int*  pos_of   = (int*)(ws + 398495744);
        int*  topk_id  = (int*)(ws + 398528512);
        float* topk_w  = (float*)(ws + 398561280);
        int*  cnt      = (int*)(ws + 398594048);
        int*  counts   = cnt;
        int*  cursors  = cnt + 8;
        int*  pad_off  = cnt + 16;

        k_init<<<1, 64, 0, stream>>>(cnt);
        k_convert<<<2048, 256, 0, stream>>>(x, xb, (long)T_TOK * HID / 8);
        k_router<<<1024, 256, 0, stream>>>(x, wr, topk_id, topk_w, counts);
        k_scan<<<1, 256, 0, stream>>>(counts, pad_off, perm_tok);
        k_scatter<<<16, 256, 0, stream>>>(topk_id, cursors, pad_off, perm_tok, pos_of);

        const long WN8 = (long)NE * FFN_D * HID / 8;
        k_convert<<<4096, 256, 0, stream>>>(w1, wA, WN8);
        k_convert<<<4096, 256, 0, stream>>>(w3, w3b, WN8);

        // stage 1: h = silu(x@w1^T)*(x@w3^T); dual-B, BK=32, 2-phase, XCD-chunked
        k_gemm_t<HID, FFN_D, 32, true, true><<<(FFN_D / BN) * 72, 256, 0, stream>>>(
            xb, wA, w3b, hb, perm_tok, pad_off);

        k_convert<<<4096, 256, 0, stream>>>(w2, wA, WN8);  // reuse w1's slot

        // stage 2: y = h @ w2^T; single-B, BK=64, 2-phase, XCD-chunked
        k_gemm_t<FFN_D, HID, 64, false, false><<<(HID / BN) * 72, 256, 0, stream>>>(
            hb, wA, (const u16*)nullptr, yb, perm_tok, pad_off);

        k_combine<<<8192, 256, 0, stream>>>(yb, pos_of, topk_w, out);
    } else {
        // ---- fallback: fp32-weight reg-staged path (~130.2 MB) ----
        u16*  xb       = (u16*)(ws);
        u16*  hbuf     = (u16*)(ws + 16777216);
        u16*  ybuf     = (u16*)(ws + 92274688);
        int*  perm_tok = (int*)(ws + 130023424);
        int*  pos_of   = (int*)(ws + 130060288);
        int*  topk_id  = (int*)(ws + 130093056);
        float* topk_w  = (float*)(ws + 130125824);
        int*  cnt      = (int*)(ws + 130158592);
        int*  counts   = cnt;
        int*  cursors  = cnt + 8;
        int*  pad_off  = cnt + 16;

        k_init<<<1, 64, 0, stream>>>(cnt);
        k_convert<<<2048, 256, 0, stream>>>(x, xb, (long)T_TOK * HID / 8);
        k_router<<<1024, 256, 0, stream>>>(x, wr, topk_id, topk_w, counts);
        k_scan<<<1, 256, 0, stream>>>(counts, pad_off, perm_tok);
        k_scatter<<<16, 256, 0, stream>>>(topk_id, cursors, pad_off, perm_tok, pos_of);

        k_gemm_fb<HID, FFN_D, true, true><<<dim3(FFN_D / BN, 32, NE), 256, 0, stream>>>(
            xb, w1, w3, hbuf, perm_tok, pad_off);
        k_gemm_fb<FFN_D, HID, false, false><<<dim3(HID / BN, 32, NE), 256, 0, stream>>>(
            hbuf, w2, (const float*)nullptr, ybuf, perm_tok, pad_off);

        k_combine<<<8192, 256, 0, stream>>>(ybuf, pos_of, topk_w, out);
    }
}